// Round 1
// baseline (157.409 us; speedup 1.0000x reference)
//
#include <hip/hip_runtime.h>

// Problem constants (fixed by the reference):
// N=4, C=32, H=W=256, KS=3, O = C*9 = 288
// p  : [4,32,32,32]   = 131072 floats  (ws offset 0)
// y  : [4,288,32,32]  = 1179648 floats (ws offset 131072)
#define N_ 4
#define C_ 32
#define H_ 256
#define W_ 256
#define O_ 288          // C*9
#define PH 32           // p spatial
#define P_ELEMS (N_*C_*PH*PH)        // 131072
#define Y_ELEMS (N_*O_*PH*PH)        // 1179648
#define OUT_ELEMS (N_*C_*H_*W_)      // 8388608

// Kernel 1: psf [N,C,256,256] -> bilinear x1/4 (exact: avg of 2x2 at rows/cols
// {4o+1,4o+2}) -> maxpool2 -> p [N,C,32,32]
__global__ __launch_bounds__(256) void k_downsample(
    const float* __restrict__ psf, float* __restrict__ p) {
  int tid = blockIdx.x * blockDim.x + threadIdx.x;
  if (tid >= P_ELEMS) return;
  int tx = tid & 31;
  int ty = (tid >> 5) & 31;
  int nc = tid >> 10;                 // n*32 + c
  const float* x = psf + (size_t)nc * (H_ * W_);
  float m = -1e30f;
#pragma unroll
  for (int a = 0; a < 2; a++) {
#pragma unroll
    for (int b = 0; b < 2; b++) {
      int r0 = 8 * ty + 4 * a + 1;
      int c0 = 8 * tx + 4 * b + 1;
      const float* row0 = x + r0 * W_ + c0;
      const float* row1 = row0 + W_;
      float avg = 0.25f * (row0[0] + row0[1] + row1[0] + row1[1]);
      m = fmaxf(m, avg);
    }
  }
  p[tid] = m;
}

// Kernel 2: y[n,o,h,w] = lrelu(sum_c p[n,c,hw]*w1[o,c] + b1[o])
//                      + (sum_c p[n,c,hw]*ws[o,c] + bs[o])
__global__ __launch_bounds__(256) void k_conv1x1(
    const float* __restrict__ p, const float* __restrict__ w1,
    const float* __restrict__ b1, const float* __restrict__ ws,
    const float* __restrict__ bs, float* __restrict__ y) {
  int idx = blockIdx.x * blockDim.x + threadIdx.x;
  if (idx >= Y_ELEMS) return;
  int n = idx / (O_ * PH * PH);
  int rem = idx - n * (O_ * PH * PH);
  int o = rem >> 10;                  // /1024
  int hw = rem & 1023;
  const float* pn = p + n * (C_ * PH * PH) + hw;
  const float* w1o = w1 + o * C_;
  const float* wso = ws + o * C_;
  float a1 = b1[o];
  float a2 = bs[o];
#pragma unroll
  for (int c = 0; c < C_; c++) {
    float pv = pn[c * (PH * PH)];
    a1 = fmaf(pv, w1o[c], a1);
    a2 = fmaf(pv, wso[c], a2);
  }
  float l = (a1 >= 0.f) ? a1 : 0.2f * a1;
  y[idx] = l + a2;
}

// Kernel 3: fused x8 bilinear upsample of y + per-pixel 3x3 dynamic filter.
// out[n,c,h,w] = sum_k fm_pad[n,c,h+dy-1,w+dx-1] * bilerp(y[n,c*9+k])(h,w)
__global__ __launch_bounds__(256) void k_fac(
    const float* __restrict__ fm, const float* __restrict__ y,
    float* __restrict__ out) {
  int idx = blockIdx.x * blockDim.x + threadIdx.x;
  if (idx >= OUT_ELEMS) return;
  int w = idx & 255;
  int h = (idx >> 8) & 255;
  int c = (idx >> 16) & 31;
  int n = idx >> 21;

  float sh = fmaxf(0.125f * (float)h - 0.4375f, 0.f);
  int y0 = (int)sh;
  float wy = sh - (float)y0;
  int y1 = min(y0 + 1, 31);
  float sw = fmaxf(0.125f * (float)w - 0.4375f, 0.f);
  int x0 = (int)sw;
  float wx = sw - (float)x0;
  int x1 = min(x0 + 1, 31);

  float w00 = (1.f - wy) * (1.f - wx);
  float w01 = (1.f - wy) * wx;
  float w10 = wy * (1.f - wx);
  float w11 = wy * wx;

  const float* yb = y + ((size_t)(n * O_ + c * 9)) * (PH * PH);
  const float* fb = fm + ((size_t)(n * C_ + c)) * (H_ * W_);

  float acc = 0.f;
#pragma unroll
  for (int k = 0; k < 9; k++) {
    const float* yk = yb + k * (PH * PH);
    float yv = w00 * yk[y0 * 32 + x0] + w01 * yk[y0 * 32 + x1] +
               w10 * yk[y1 * 32 + x0] + w11 * yk[y1 * 32 + x1];
    int dy = k / 3 - 1, dx = k % 3 - 1;
    int hh = h + dy, ww = w + dx;
    float fv = (hh >= 0 && hh < 256 && ww >= 0 && ww < 256)
                   ? fb[hh * 256 + ww] : 0.f;
    acc = fmaf(fv, yv, acc);
  }
  out[idx] = acc;
}

extern "C" void kernel_launch(void* const* d_in, const int* in_sizes, int n_in,
                              void* d_out, int out_size, void* d_ws,
                              size_t ws_size, hipStream_t stream) {
  const float* psf = (const float*)d_in[0];
  const float* fm = (const float*)d_in[1];
  const float* w1 = (const float*)d_in[2];
  const float* b1 = (const float*)d_in[3];
  const float* ws = (const float*)d_in[4];
  const float* bs = (const float*)d_in[5];
  float* out = (float*)d_out;

  float* p = (float*)d_ws;
  float* y = p + P_ELEMS;

  k_downsample<<<P_ELEMS / 256, 256, 0, stream>>>(psf, p);
  k_conv1x1<<<Y_ELEMS / 256, 256, 0, stream>>>(p, w1, b1, ws, bs, y);
  k_fac<<<OUT_ELEMS / 256, 256, 0, stream>>>(fm, y, out);
}

// Round 2
// 131.803 us; speedup vs baseline: 1.1943x; 1.1943x over previous
//
#include <hip/hip_runtime.h>

// N=4, C=32, H=W=256, KS=3, O=C*9=288
// ws layout: p [4,32,32,32] (131072 f) | y [4,288,32,32] (1179648 f)
#define N_ 4
#define C_ 32
#define H_ 256
#define W_ 256
#define O_ 288
#define PH 32
#define P_ELEMS (N_*C_*PH*PH)
#define Y_ELEMS (N_*O_*PH*PH)
#define OUT_ELEMS (N_*C_*H_*W_)

// Kernel 1: psf -> 1/4 bilinear (avg of 2x2 at rows/cols {4o+1,4o+2}) -> maxpool2
__global__ __launch_bounds__(256) void k_downsample(
    const float* __restrict__ psf, float* __restrict__ p) {
  int tid = blockIdx.x * blockDim.x + threadIdx.x;
  if (tid >= P_ELEMS) return;
  int tx = tid & 31;
  int ty = (tid >> 5) & 31;
  int nc = tid >> 10;
  const float* x = psf + (size_t)nc * (H_ * W_);
  float m = -1e30f;
#pragma unroll
  for (int a = 0; a < 2; a++) {
#pragma unroll
    for (int b = 0; b < 2; b++) {
      int r0 = 8 * ty + 4 * a + 1;
      int c0 = 8 * tx + 4 * b + 1;
      const float* row0 = x + r0 * W_ + c0;
      const float* row1 = row0 + W_;
      float avg = 0.25f * (row0[0] + row0[1] + row1[0] + row1[1]);
      m = fmaxf(m, avg);
    }
  }
  p[tid] = m;
}

// Kernel 2: one block per (n,o); weights are block-uniform (scalar loads).
// Each thread computes 4 consecutive hw via float4.
__global__ __launch_bounds__(256) void k_conv1x1(
    const float* __restrict__ p, const float* __restrict__ w1,
    const float* __restrict__ b1, const float* __restrict__ ws,
    const float* __restrict__ bs, float* __restrict__ y) {
  int bid = blockIdx.x;           // n*O_ + o
  int n = bid / O_;
  int o = bid - n * O_;
  const float4* p4 = (const float4*)(p + (size_t)n * (C_ * PH * PH));
  const float* w1o = w1 + o * C_;
  const float* wso = ws + o * C_;
  float bb1 = b1[o];
  float bbs = bs[o];
  int t = threadIdx.x;            // t*4 .. t*4+3 of 1024 hw
  float a1x = bb1, a1y = bb1, a1z = bb1, a1w = bb1;
  float a2x = bbs, a2y = bbs, a2z = bbs, a2w = bbs;
#pragma unroll
  for (int c = 0; c < C_; c++) {
    float4 pv = p4[c * 256 + t];
    float u1 = w1o[c], u2 = wso[c];
    a1x = fmaf(pv.x, u1, a1x); a1y = fmaf(pv.y, u1, a1y);
    a1z = fmaf(pv.z, u1, a1z); a1w = fmaf(pv.w, u1, a1w);
    a2x = fmaf(pv.x, u2, a2x); a2y = fmaf(pv.y, u2, a2y);
    a2z = fmaf(pv.z, u2, a2z); a2w = fmaf(pv.w, u2, a2w);
  }
  float4 r;
  r.x = ((a1x >= 0.f) ? a1x : 0.2f * a1x) + a2x;
  r.y = ((a1y >= 0.f) ? a1y : 0.2f * a1y) + a2y;
  r.z = ((a1z >= 0.f) ? a1z : 0.2f * a1z) + a2z;
  r.w = ((a1w >= 0.f) ? a1w : 0.2f * a1w) + a2w;
  ((float4*)(y + (size_t)bid * (PH * PH)))[t] = r;
}

// Kernel 3: fused x8 bilinear upsample + per-pixel 3x3 dynamic filter.
// 8 outputs/thread along w (one aligned group). For w=8m+j:
//   j<4 : x0=m-1, wx=0.5625+0.125j  -> lerp between cols (m-1, m)
//   j>=4: x0=m,   wx=0.0625+0.125(j-4) -> lerp between cols (m, m+1)
// Clamped edge columns give d=0 so the same formula is exact at borders.
__global__ __launch_bounds__(256) void k_fac(
    const float* __restrict__ fm, const float* __restrict__ y,
    float* __restrict__ out) {
  // XCD swizzle: 4096 blocks, assume xcd = blockIdx % 8; give each XCD a
  // contiguous work range so it owns whole (n,c) y-planes.
  int bid = blockIdx.x;
  int work = (bid >> 3) + (bid & 7) * 512;
  int g = (work << 8) + threadIdx.x;   // group id, 8 outputs each
  int m = g & 31;                      // w-group: w = 8m+j
  int h = (g >> 5) & 255;
  int c = (g >> 13) & 31;
  int n = g >> 18;

  // vertical interp for this h
  float sh = fmaxf(0.125f * (float)h - 0.4375f, 0.f);
  int y0 = (int)sh;
  float wy = sh - (float)y0;
  int y1 = min(y0 + 1, 31);

  int cm1 = max(m - 1, 0);
  int cp1 = min(m + 1, 31);
  int ro0 = y0 * 32, ro1 = y1 * 32;

  const float* yb = y + ((size_t)(n * O_ + c * 9) << 10);
  const float* fb = fm + ((size_t)(n * C_ + c) << 16);

  float acc0 = 0.f, acc1 = 0.f, acc2 = 0.f, acc3 = 0.f;
  float acc4 = 0.f, acc5 = 0.f, acc6 = 0.f, acc7 = 0.f;

#pragma unroll
  for (int ky = 0; ky < 3; ky++) {
    int row = h + ky - 1;
    float fv[10];
    if (row >= 0 && row < 256) {
      const float* fr = fb + row * 256 + (m << 3);
      float4 q0 = *(const float4*)(fr);
      float4 q1 = *(const float4*)(fr + 4);
      fv[0] = (m > 0) ? fr[-1] : 0.f;
      fv[1] = q0.x; fv[2] = q0.y; fv[3] = q0.z; fv[4] = q0.w;
      fv[5] = q1.x; fv[6] = q1.y; fv[7] = q1.z; fv[8] = q1.w;
      fv[9] = (m < 31) ? fr[8] : 0.f;
    } else {
#pragma unroll
      for (int t = 0; t < 10; t++) fv[t] = 0.f;
    }
#pragma unroll
    for (int kx = 0; kx < 3; kx++) {
      const float* yp = yb + ((3 * ky + kx) << 10);
      float t0 = yp[ro0 + cm1], t1 = yp[ro0 + m], t2 = yp[ro0 + cp1];
      float u0 = yp[ro1 + cm1], u1 = yp[ro1 + m], u2 = yp[ro1 + cp1];
      float tb0 = fmaf(wy, u0 - t0, t0);
      float tb1 = fmaf(wy, u1 - t1, t1);
      float tb2 = fmaf(wy, u2 - t2, t2);
      float d0 = tb1 - tb0;
      float d1 = tb2 - tb1;
      float yv0 = fmaf(0.5625f, d0, tb0);
      float yv1 = fmaf(0.6875f, d0, tb0);
      float yv2 = fmaf(0.8125f, d0, tb0);
      float yv3 = fmaf(0.9375f, d0, tb0);
      float yv4 = fmaf(0.0625f, d1, tb1);
      float yv5 = fmaf(0.1875f, d1, tb1);
      float yv6 = fmaf(0.3125f, d1, tb1);
      float yv7 = fmaf(0.4375f, d1, tb1);
      acc0 = fmaf(fv[0 + kx], yv0, acc0);
      acc1 = fmaf(fv[1 + kx], yv1, acc1);
      acc2 = fmaf(fv[2 + kx], yv2, acc2);
      acc3 = fmaf(fv[3 + kx], yv3, acc3);
      acc4 = fmaf(fv[4 + kx], yv4, acc4);
      acc5 = fmaf(fv[5 + kx], yv5, acc5);
      acc6 = fmaf(fv[6 + kx], yv6, acc6);
      acc7 = fmaf(fv[7 + kx], yv7, acc7);
    }
  }
  float* ob = out + ((size_t)(((n * C_ + c) << 8) + h) << 8) + (m << 3);
  float4 r0 = {acc0, acc1, acc2, acc3};
  float4 r1 = {acc4, acc5, acc6, acc7};
  *(float4*)(ob) = r0;
  *(float4*)(ob + 4) = r1;
}

extern "C" void kernel_launch(void* const* d_in, const int* in_sizes, int n_in,
                              void* d_out, int out_size, void* d_ws,
                              size_t ws_size, hipStream_t stream) {
  const float* psf = (const float*)d_in[0];
  const float* fm = (const float*)d_in[1];
  const float* w1 = (const float*)d_in[2];
  const float* b1 = (const float*)d_in[3];
  const float* ws = (const float*)d_in[4];
  const float* bs = (const float*)d_in[5];
  float* out = (float*)d_out;

  float* p = (float*)d_ws;
  float* y = p + P_ELEMS;

  k_downsample<<<P_ELEMS / 256, 256, 0, stream>>>(psf, p);
  k_conv1x1<<<N_ * O_, 256, 0, stream>>>(p, w1, b1, ws, bs, y);
  k_fac<<<OUT_ELEMS / (8 * 256), 256, 0, stream>>>(fm, y, out);
}